// Round 7
// baseline (125.811 us; speedup 1.0000x reference)
//
#include <hip/hip_runtime.h>

#define CCH   256      // channels
#define HIDN  64       // hidden
#define GK    144      // groups * 9
#define NB    8        // batch
#define NHW   4096     // 64*64

// ws layout (floats): w1T4[64 c4][64 o][4 cc] | w2T[64 o][144 j]
#define W1T_OFF  0
#define W2T_OFF  16384

// ---------------------------------------------------------------------------
// Kernel 0: repack weights.
//  w1T4[c4][o][cc] = w_reduce[o][c4*4+cc]  -> per-lane float4 loads in phase 1
//  w2T[o][j]       = w_span[j][o]
// ---------------------------------------------------------------------------
__global__ __launch_bounds__(256) void wtrans_kernel(
    const float* __restrict__ w_reduce, const float* __restrict__ w_span,
    float* __restrict__ ws)
{
    const int idx = blockIdx.x * 256 + threadIdx.x;   // 100 blocks * 256 = 25600
    if (idx < 16384) {
        const int cc = idx & 3, o = (idx >> 2) & 63, c4 = idx >> 8;
        ws[W1T_OFF + idx] = w_reduce[o * CCH + c4 * 4 + cc];
    } else {
        const int i2 = idx - 16384;                   // < 9216
        const int o = i2 / 144, j = i2 - o * 144;
        ws[W2T_OFF + i2] = w_span[j * HIDN + o];
    }
}

// ---------------------------------------------------------------------------
// Fused involution: block = 512 threads (8 waves) = one image row (64 px).
// phase 1: lane = o (hidden ch). Wave w owns pixels [8w, 8w+8).
//          weights per-lane vector loads (vmcnt), x uniform ds_read (lgkm).
// phase 2: lane = px. w_span read from LDS (staged once), hid from LDS.
//          kv[18] (= groups {2w,2w+1}) stays in registers.
// apply  : lane = px, 32 channels per wave, border mask folded into kv.
// ---------------------------------------------------------------------------
__global__ __launch_bounds__(512, 4) void invol_fused(
    const float* __restrict__ x,        // [B,256,64,64]
    const float* __restrict__ b_reduce, // [64]
    const float* __restrict__ b_span,   // [144]
    const float* __restrict__ ws_ro,    // w1T4 / w2T
    float* __restrict__ out)            // [B,256,64,64]
{
    __shared__ __align__(16) float smem[16384];   // 64 KB
    float (*xs)[64] = (float (*)[64])smem;        // phase 1: [c][px]
    // after phase 1: w2s = smem[0 .. 10240)  ([o][8w][20] padded)
    //                hid = smem[10240 .. 14400)  ([px][65])
    float* const w2s = smem;
    float* const hid = smem + 10240;

    const int lane = threadIdx.x & 63;
    const int wid  = __builtin_amdgcn_readfirstlane(threadIdx.x >> 6);
    const int tid  = threadIdx.x;

    const int raw = blockIdx.x;                   // [0, 512)
    const int row = ((raw & 7) << 6) | (raw >> 3);// bijective XCD chunk swizzle
    const int b   = row >> 6;
    const int hr  = row & 63;

    const float* xb = x + (size_t)b * (CCH * NHW) + hr * 64;

    // ---- stage whole x row (256 ch x 64 px = 64 KB) via global_load_lds ----
    {
        const int cl = lane >> 4;                 // sub-channel 0..3
        const int p4 = (lane & 15) * 4;
        #pragma unroll
        for (int t = 0; t < 8; ++t) {
            const int c0 = wid * 32 + t * 4;
            const float* src = xb + (size_t)(c0 + cl) * NHW + p4;
            __builtin_amdgcn_global_load_lds(
                (const __attribute__((address_space(1))) unsigned int*)src,
                (__attribute__((address_space(3))) unsigned int*)&xs[c0][0],
                16, 0, 0);
        }
    }
    __syncthreads();

    // ---- phase 1: lane = o. acc[p] = hid[o][p8+p] for 8 pixels ----
    const int p8 = wid * 8;
    const float4* w1p = (const float4*)(ws_ro + W1T_OFF);   // [c4*64 + o]
    float acc[8];
    {
        const float bias = b_reduce[lane];        // per-lane vector load
        #pragma unroll
        for (int p = 0; p < 8; ++p) acc[p] = bias;
    }

    #pragma unroll 4
    for (int c4 = 0; c4 < 64; ++c4) {
        const float4 wv = w1p[c4 * 64 + lane];    // per-lane, coalesced, vmcnt
        #pragma unroll
        for (int cc = 0; cc < 4; ++cc) {
            const int c = c4 * 4 + cc;
            const float4 x0 = *(const float4*)&xs[c][p8];     // uniform bcast
            const float4 x1 = *(const float4*)&xs[c][p8 + 4]; // uniform bcast
            const float wcc = (cc == 0) ? wv.x : (cc == 1) ? wv.y
                            : (cc == 2) ? wv.z : wv.w;
            acc[0] = fmaf(wcc, x0.x, acc[0]);
            acc[1] = fmaf(wcc, x0.y, acc[1]);
            acc[2] = fmaf(wcc, x0.z, acc[2]);
            acc[3] = fmaf(wcc, x0.w, acc[3]);
            acc[4] = fmaf(wcc, x1.x, acc[4]);
            acc[5] = fmaf(wcc, x1.y, acc[5]);
            acc[6] = fmaf(wcc, x1.z, acc[6]);
            acc[7] = fmaf(wcc, x1.w, acc[7]);
        }
    }
    __syncthreads();                              // xs dead; safe to overlay

    // ---- write hid (relu) + stage w2 slice into LDS ----
    #pragma unroll
    for (int p = 0; p < 8; ++p)
        hid[(p8 + p) * 65 + lane] = fmaxf(acc[p], 0.0f);

    {   // thread (o2, w8) copies w2T[o2][w8*18 .. +18) -> w2s[o2*160 + w8*20]
        const int o2 = tid >> 3, w8 = tid & 7;
        const float2* src = (const float2*)(ws_ro + W2T_OFF + o2 * 144 + w8 * 18);
        float2* dst = (float2*)(w2s + o2 * 160 + w8 * 20);
        #pragma unroll
        for (int r = 0; r < 9; ++r) dst[r] = src[r];
    }
    __syncthreads();

    // ---- phase 2: lane = px. kv[18] for groups {2w, 2w+1} ----
    const int j0 = wid * 18;
    float kv[18];
    #pragma unroll
    for (int jj = 0; jj < 18; ++jj) kv[jj] = b_span[j0 + jj];

    #pragma unroll 2
    for (int o = 0; o < HIDN; ++o) {
        const float hv = hid[lane * 65 + o];      // conflict-free (stride 65)
        const float4* wp = (const float4*)(w2s + o * 160 + wid * 20);
        const float4 wa = wp[0], wb = wp[1], wc = wp[2], wd = wp[3];
        const float2 we = *(const float2*)(w2s + o * 160 + wid * 20 + 16);
        kv[ 0] = fmaf(wa.x, hv, kv[ 0]);  kv[ 1] = fmaf(wa.y, hv, kv[ 1]);
        kv[ 2] = fmaf(wa.z, hv, kv[ 2]);  kv[ 3] = fmaf(wa.w, hv, kv[ 3]);
        kv[ 4] = fmaf(wb.x, hv, kv[ 4]);  kv[ 5] = fmaf(wb.y, hv, kv[ 5]);
        kv[ 6] = fmaf(wb.z, hv, kv[ 6]);  kv[ 7] = fmaf(wb.w, hv, kv[ 7]);
        kv[ 8] = fmaf(wc.x, hv, kv[ 8]);  kv[ 9] = fmaf(wc.y, hv, kv[ 9]);
        kv[10] = fmaf(wc.z, hv, kv[10]);  kv[11] = fmaf(wc.w, hv, kv[11]);
        kv[12] = fmaf(wd.x, hv, kv[12]);  kv[13] = fmaf(wd.y, hv, kv[13]);
        kv[14] = fmaf(wd.z, hv, kv[14]);  kv[15] = fmaf(wd.w, hv, kv[15]);
        kv[16] = fmaf(we.x, hv, kv[16]);  kv[17] = fmaf(we.y, hv, kv[17]);
    }

    // ---- fold border mask into kv ----
    const bool vwm = (lane > 0), vwp = (lane < 63);
    const bool vhm = (hr  > 0), vhp = (hr  < 63);
    const bool vk[9] = { vhm && vwm, vhm, vhm && vwp,
                         vwm,        true, vwp,
                         vhp && vwm, vhp, vhp && vwp };
    #pragma unroll
    for (int jj = 0; jj < 18; ++jj)
        kv[jj] = vk[jj % 9] ? kv[jj] : 0.0f;

    // ---- apply: 32 channels (2 groups) per wave, 9 taps each ----
    const int oWm = vwm ? -1  : 0, oWp = vwp ? 1  : 0;
    const int oHm = vhm ? -64 : 0, oHp = vhp ? 64 : 0;
    const int oo[9] = { oHm + oWm, oHm, oHm + oWp,
                        oWm,       0,   oWp,
                        oHp + oWm, oHp, oHp + oWp };

    const float* xrow = xb + lane;
    float*       orow = out + (size_t)b * (CCH * NHW) + hr * 64 + lane;

    #pragma unroll 4
    for (int m = 0; m < 32; ++m) {
        const int c  = wid * 32 + m;
        const int gl = m >> 4;                    // group-local 0/1
        const float* xc = xrow + (size_t)c * NHW;
        float a = 0.0f;
        #pragma unroll
        for (int k = 0; k < 9; ++k)
            a = fmaf(xc[oo[k]], kv[gl * 9 + k], a);
        orow[(size_t)c * NHW] = a;
    }
}

// ---------------------------------------------------------------------------
extern "C" void kernel_launch(void* const* d_in, const int* in_sizes, int n_in,
                              void* d_out, int out_size, void* d_ws, size_t ws_size,
                              hipStream_t stream) {
    const float* x        = (const float*)d_in[0];
    const float* w_reduce = (const float*)d_in[1];
    const float* b_reduce = (const float*)d_in[2];
    const float* w_span   = (const float*)d_in[3];
    const float* b_span   = (const float*)d_in[4];
    float* out = (float*)d_out;
    float* ws  = (float*)d_ws;    // needs 102400 B

    wtrans_kernel<<<dim3(100), dim3(256), 0, stream>>>(w_reduce, w_span, ws);
    invol_fused<<<dim3(NB * 64), dim3(512), 0, stream>>>(
        x, b_reduce, b_span, ws, out);
}